// Round 10
// baseline (365.698 us; speedup 1.0000x reference)
//
#include <hip/hip_runtime.h>
#include <hip/hip_fp16.h>
#include <math.h>

#define HDIM 128

#define BSHIFT 7
#define BW 128                  // nodes per bucket (dst >> 7)
#define BCAP 4096               // slots per bucket (mean fill 2048, +45 sigma)
#define NBKMAX 1024
#define CHUNK 2048              // edges per binning block (782 blocks: 3/CU)

typedef __attribute__((ext_vector_type(8))) _Float16 f16x8;
typedef __attribute__((ext_vector_type(2))) _Float16 f16x2;
typedef __attribute__((ext_vector_type(16))) float f32x16;
typedef unsigned int uint32;
typedef unsigned short u16;

// packed fp16 max -> v_pk_max_f16
__device__ __forceinline__ uint32 hmax2u(uint32 a, uint32 b) {
    f16x2 ha = __builtin_bit_cast(f16x2, a);
    f16x2 hb = __builtin_bit_cast(f16x2, b);
    f16x2 r = __builtin_elementwise_max(ha, hb);
    return __builtin_bit_cast(uint32, r);
}
// packed fp16 add -> v_pk_add_f16
__device__ __forceinline__ uint32 hadd2u(uint32 a, uint32 b) {
    f16x2 ha = __builtin_bit_cast(f16x2, a);
    f16x2 hb = __builtin_bit_cast(f16x2, b);
    f16x2 r = ha + hb;
    return __builtin_bit_cast(uint32, r);
}

// ---------------- prep: bucket-bin (FIRST) | weights-pack | x-cast ------------
// Bin role first: heavy blocks start at t=0 on all CUs; 25k tiny cast blocks
// backfill as they retire. Bin body = LDS-privatized two-pass (run-coalesced
// tmp writes — rounds 7/8 proved per-edge global-atomic scatter write-amps 2x).

__global__ __launch_bounds__(256) void prep(
    const float* __restrict__ x, const int* __restrict__ ei,
    const float* __restrict__ W1l, const float* __restrict__ W1r,
    const float* __restrict__ W2l, const float* __restrict__ W2r,
    const float* __restrict__ W3l, const float* __restrict__ W3r,
    f16x8* __restrict__ PW, uint32* __restrict__ xb,
    int* __restrict__ bucketCnt, uint32* __restrict__ tmp,
    int E_, int N_, int nbk, int nbB, int nbW)
{
    __shared__ int cnt[NBKMAX];
    __shared__ int gbase[NBKMAX];
    const int bid = blockIdx.x, t = threadIdx.x;

    if (bid < nbB) {
        // ---- bucket binning
        const int start = bid * CHUNK;
        const int end = min(start + CHUNK, E_);
        for (int i = t; i < nbk; i += 256) cnt[i] = 0;
        __syncthreads();
        for (int e = start + t; e < end; e += 256)
            atomicAdd(&cnt[ei[E_ + e] >> BSHIFT], 1);
        __syncthreads();
        for (int i = t; i < nbk; i += 256) {
            int c = cnt[i];
            gbase[i] = c ? atomicAdd(&bucketCnt[i], c) : 0;
        }
        __syncthreads();
        for (int i = t; i < nbk; i += 256) cnt[i] = 0;
        __syncthreads();
        for (int e = start + t; e < end; e += 256) {
            int d = ei[E_ + e];
            int s = ei[e];
            int b = d >> BSHIFT;
            int r = atomicAdd(&cnt[b], 1);
            tmp[(size_t)b * BCAP + gbase[b] + r] =
                ((uint32)(d & (BW - 1)) << 17) | (uint32)s;
        }
    } else if (bid < nbB + nbW) {
        // ---- weights: 3*4096 frags
        // PW[layer][(g*16+ks)*64+lane] = 16B frag; elements =
        // W[col=g*32+(lane&31)][(ks&7)*16 + (lane>>5)*8 + j], ks<8 -> Wl else Wr
        int tid = (bid - nbB) * 256 + t;
        if (tid >= 3 * 4096) return;
        int layer = tid >> 12, rem = tid & 4095;
        int g = rem >> 10, ks = (rem >> 6) & 15, lane = rem & 63;
        int col = g * 32 + (lane & 31), kq = lane >> 5;
        const float* src;
        if (layer == 0)      src = (ks < 8) ? W1l : W1r;
        else if (layer == 1) src = (ks < 8) ? W2l : W2r;
        else                 src = (ks < 8) ? W3l : W3r;
        int kk = (ks & 7) * 16 + kq * 8;
        f16x8 v;
#pragma unroll
        for (int j = 0; j < 8; ++j) v[j] = (_Float16)src[col * HDIM + kk + j];
        PW[tid] = v;
    } else {
        // ---- cast x -> packed half2
        int i = (bid - nbB - nbW) * 256 + t;
        if (i >= N_ * 64) return;
        float2 v = ((const float2*)x)[i];
        f16x2 h = { (_Float16)v.x, (_Float16)v.y };
        xb[i] = __builtin_bit_cast(uint32, h);
    }
}

// ---------------- bucket_csr: inline base-scan + LDS-staged sort --------------
// R7's inline scan (each block redundantly computes its base from bucketCnt:
// 782 L2-resident ints, ~us) + R9's LDS scatter with LINEAR global srcs store
// (rounds 7/8: scattered 4B global writes cost a 64B write-allocate line each).
// Replaces the separate bucket_scan dispatch.

__global__ __launch_bounds__(256) void bucket_csr(
    const uint32* __restrict__ tmp, const int* __restrict__ bucketCnt,
    int* __restrict__ off, int* __restrict__ srcs, int N_, int E_, int nbk)
{
    __shared__ uint32 stmp[BCAP];    // 16 KB staged bucket entries
    __shared__ int sout[BCAP];       // 16 KB sorted srcs
    __shared__ int lc[BW];
    __shared__ int lo[BW];
    __shared__ int sd[256];
    __shared__ int sbase;
    const int b = blockIdx.x, t = threadIdx.x;
    const int cnt = bucketCnt[b];
    const uint32* tp = tmp + (size_t)b * BCAP;

    // stage bucket (coalesced reads) — overlaps the base-scan below
    for (int i = t; i < cnt; i += 256) stmp[i] = tp[i];

    // inline scan for this bucket's base: thread t sums bucketCnt[4t..4t+4)
    int p = 0;
#pragma unroll
    for (int k = 0; k < 4; ++k) {
        int i = 4 * t + k;
        p += (i < nbk) ? bucketCnt[i] : 0;
    }
    sd[t] = p;
    if (t < BW) lc[t] = 0;
    __syncthreads();
    for (int ofs = 1; ofs < 256; ofs <<= 1) {
        int add = (t >= ofs) ? sd[t - ofs] : 0;
        __syncthreads();
        sd[t] += add;
        __syncthreads();
    }
    if (t == 0) {
        int c = b >> 2;
        int base = c ? sd[c - 1] : 0;
        for (int i = 4 * c; i < b; ++i) base += bucketCnt[i];
        sbase = base;
        if (b == 0) off[N_] = E_;
    }
    __syncthreads();
    const int base = sbase;

    // per-node histogram (LDS atomics on LDS data)
    for (int i = t; i < cnt; i += 256) atomicAdd(&lc[stmp[i] >> 17], 1);
    __syncthreads();

    // 128-bin exclusive scan
    int v = (t < BW) ? lc[t] : 0;
    sd[t] = v;
    __syncthreads();
    for (int ofs = 1; ofs < 256; ofs <<= 1) {
        int add = (t >= ofs) ? sd[t - ofs] : 0;
        __syncthreads();
        sd[t] += add;
        __syncthreads();
    }
    if (t < BW) lo[t] = sd[t] - v;
    __syncthreads();

    // node offsets (coalesced)
    for (int i = t; i < BW; i += 256) {
        int node = b * BW + i;
        if (node < N_) off[node] = base + lo[i];
    }
    if (t < BW) lc[t] = lo[t];
    __syncthreads();

    // scatter WITHIN LDS (cheap), then linear coalesced global store
    for (int i = t; i < cnt; i += 256) {
        uint32 p2 = stmp[i];
        int pos = atomicAdd(&lc[p2 >> 17], 1);
        sout[pos] = (int)(p2 & 0x1FFFF);
    }
    __syncthreads();
    for (int i = t; i < cnt; i += 256) srcs[base + i] = sout[i];
}

// ---------------- fused layer (verbatim round-5/9 structure — DO NOT TOUCH) ---
// gather-max (LDS-staged edge indices + software-pipelined feature loads)
//   -> GEMM -> ELU(+res from staged sh tile) [-> readout]
// At its pattern ceiling: 186 MB L2-fill at the ~3.2-3.5 TB/s random-256B rate
// (reproduced across 5 structures, R0/R1/R2/R5/R9) ~= the 68.5 us measured.
//
// LDS: sm/ho overlay 8704 + sh 8192 + soff 132 + sedge 3328 = 20356 B.
// launch_bounds(256,6): VGPR cap ~84 so the vb[2][4] pipeline (needs ~60)
// actually lives in registers (cap 64 sank it: VGPR=32 + scratch spills).

#define ESTRIDE 136     // halves per epilogue LDS row (272 B)
#define EDGE_CAP 832    // staged edges per block (mean 512, std 22.6 -> +14 sigma)

#define RED16(m0,m1,m2,m3,V) do { \
    m0 = hmax2u(m0, (V)[0].x); m1 = hmax2u(m1, (V)[0].y); \
    m2 = hmax2u(m2, (V)[0].z); m3 = hmax2u(m3, (V)[0].w); \
    m0 = hmax2u(m0, (V)[1].x); m1 = hmax2u(m1, (V)[1].y); \
    m2 = hmax2u(m2, (V)[1].z); m3 = hmax2u(m3, (V)[1].w); \
    m0 = hmax2u(m0, (V)[2].x); m1 = hmax2u(m1, (V)[2].y); \
    m2 = hmax2u(m2, (V)[2].z); m3 = hmax2u(m3, (V)[2].w); \
    m0 = hmax2u(m0, (V)[3].x); m1 = hmax2u(m1, (V)[3].y); \
    m2 = hmax2u(m2, (V)[3].z); m3 = hmax2u(m3, (V)[3].w); \
} while (0)

// issue one 16-edge batch (4 uint4/lane), edge indices clamped to [*, e1-1]
// (duplicates are idempotent under max); L=true reads indices from LDS.
template<bool L>
__device__ __forceinline__ void issue_batch(
    const uint4* __restrict__ hp, const int* __restrict__ srcs,
    const int* sedge, int estart, int eb, int e1, int es, int ch, uint4* v)
{
    int last = e1 - 1;
#pragma unroll
    for (int k = 0; k < 4; ++k) {
        int idx = min(eb + es + 4 * k, last);
        int s = L ? sedge[idx - estart] : srcs[idx];
        v[k] = hp[(size_t)s * 16 + ch];
    }
}

template<bool L>
__device__ __forceinline__ void gather8(
    const uint4* __restrict__ hp, const int* __restrict__ srcs,
    const int* sedge, int estart, int offv, int es, int ch, int w,
    uint4* sm)
{
    const uint32 NINF = 0xFC00FC00u;   // half2(-inf,-inf)
    uint4 vb[2][4];

    int e0 = __shfl(offv, 0), e1 = __shfl(offv, 1);
    bool has = e1 > e0;
    if (has) issue_batch<L>(hp, srcs, sedge, estart, e0, e1, es, ch, vb[0]);

#pragma unroll
    for (int i = 0; i < 8; ++i) {
        // prefetch next node's first batch while current reduces
        int e0n = 0, e1n = 0; bool hasn = false;
        if (i + 1 < 8) {
            e0n = __shfl(offv, i + 1); e1n = __shfl(offv, i + 2);
            hasn = e1n > e0n;
            if (hasn) issue_batch<L>(hp, srcs, sedge, estart, e0n, e1n, es, ch, vb[(i + 1) & 1]);
        }
        uint32 m0 = NINF, m1 = NINF, m2 = NINF, m3 = NINF;
        if (has) {
            RED16(m0, m1, m2, m3, vb[i & 1]);
            for (int eb = e0 + 16; eb < e1; eb += 16) {   // extra batches (deg>16)
                issue_batch<L>(hp, srcs, sedge, estart, eb, e1, es, ch, vb[i & 1]);
                RED16(m0, m1, m2, m3, vb[i & 1]);
            }
        }
        m0 = hmax2u(m0, __shfl_xor(m0, 16)); m0 = hmax2u(m0, __shfl_xor(m0, 32));
        m1 = hmax2u(m1, __shfl_xor(m1, 16)); m1 = hmax2u(m1, __shfl_xor(m1, 32));
        m2 = hmax2u(m2, __shfl_xor(m2, 16)); m2 = hmax2u(m2, __shfl_xor(m2, 32));
        m3 = hmax2u(m3, __shfl_xor(m3, 16)); m3 = hmax2u(m3, __shfl_xor(m3, 32));
        if (es == 0) {
            int row = w * 8 + i;
            uint4 rr = make_uint4(0u, 0u, 0u, 0u);   // empty/padded -> 0 (PyG)
            if (has) { rr.x = m0; rr.y = m1; rr.z = m2; rr.w = m3; }
            sm[row * 16 + (ch ^ (row & 7))] = rr;
        }
        e0 = e0n; e1 = e1n; has = hasn;
    }
}

__global__ __launch_bounds__(256, 6) void fused_layer(
    const uint32* __restrict__ hb,      // [Np,64] input features, packed half2
    const int* __restrict__ off, const int* __restrict__ srcs,
    uint4* __restrict__ outb,           // layer output (null => readout mode)
    const uint4* __restrict__ PW,       // [4096] packed weight frags, this layer
    const float* __restrict__ bias,
    int use_res,
    const float* __restrict__ Wo, const float* __restrict__ bo,
    float* __restrict__ out, int n_nodes)
{
    __shared__ alignas(16) char smemA[32 * ESTRIDE * 2];  // 8704 B: sm / ho overlay
    __shared__ uint4 sh[512];                             // 8192 B: h-tile
    __shared__ int soff[33];                              // 132 B
    __shared__ int sedge[EDGE_CAP];                       // 3328 B
    uint4*     sm = (uint4*)smemA;
    _Float16*  ho = (_Float16*)smemA;

    const int t = threadIdx.x, lane = t & 63, w = t >> 6;
    const int base = blockIdx.x * 32;
    const int l31 = lane & 31, kq = lane >> 5;
    const uint4* hp = (const uint4*)hb;

    // stage off[] window
    if (t < 33) soff[t] = off[min(base + t, n_nodes)];

    // stage h-tile, coalesced, swizzled (loads overlap edge staging)
#pragma unroll
    for (int r = 0; r < 2; ++r) {
        int g = r * 256 + t;            // 0..511
        int row = g >> 4, c = g & 15;
        sh[row * 16 + (c ^ (row & 7))] = hp[(size_t)(base + row) * 16 + c];
    }

    // stage the block's contiguous CSR edge range into LDS (coalesced)
    const int estart = off[base];
    const int eend = off[min(base + 32, n_nodes)];
    const int ecnt = eend - estart;
    const bool useLds = (ecnt <= EDGE_CAP);   // block-uniform
    const int scount = useLds ? ecnt : 0;
    for (int i = t; i < scount; i += 256) sedge[i] = srcs[estart + i];
    __syncthreads();

    // gather-max: each wave aggregates 8 nodes, result into swizzled sm
    const int es = lane >> 4, ch = lane & 15;
    const int offv = soff[w * 8 + min(lane, 8)];
    if (useLds) gather8<true >(hp, srcs, sedge, estart, offv, es, ch, w, sm);
    else        gather8<false>(hp, srcs, sedge, estart, offv, es, ch, w, sm);
    __syncthreads();

    f32x16 acc = {};
#pragma unroll
    for (int k = 0; k < 8; ++k) {   // m half, K=0..127
        f16x8 a = __builtin_bit_cast(f16x8, sm[l31 * 16 + ((2 * k + kq) ^ (l31 & 7))]);
        f16x8 b = __builtin_bit_cast(f16x8, PW[(w * 16 + k) * 64 + lane]);
        acc = __builtin_amdgcn_mfma_f32_32x32x16_f16(a, b, acc, 0, 0, 0);
    }
#pragma unroll
    for (int k = 0; k < 8; ++k) {   // h half, K=128..255
        f16x8 a = __builtin_bit_cast(f16x8, sh[l31 * 16 + ((2 * k + kq) ^ (l31 & 7))]);
        f16x8 b = __builtin_bit_cast(f16x8, PW[(w * 16 + 8 + k) * 64 + lane]);
        acc = __builtin_amdgcn_mfma_f32_32x32x16_f16(a, b, acc, 0, 0, 0);
    }

    __syncthreads();   // all waves done reading sm before ho overlay is written

    // epilogue phase 1: bias + ELU in fp32, fp16 into LDS transpose tile
    // C/D layout (32x32): col = lane&31, row = (reg&3)+8*(reg>>2)+4*(lane>>5)
    const int C = w * 32 + l31;
    const float bv = bias[C];
#pragma unroll
    for (int r = 0; r < 16; ++r) {
        int row = (r & 3) + 8 * (r >> 2) + 4 * kq;
        float v = acc[r] + bv;
        v = (v > 0.f) ? v : (__expf(v) - 1.f);
        ho[row * ESTRIDE + C] = (_Float16)v;
    }
    __syncthreads();

    // epilogue phase 2: residual from staged sh tile; store row-major uint4,
    // or (layer 3) fused readout without materializing h3.
#pragma unroll
    for (int r = 0; r < 2; ++r) {
        int g = r * 256 + t;            // 0..511
        int row = g >> 4, c = g & 15;
        int R = base + row;
        bool valid = (R < n_nodes);
        uint4 v = *(const uint4*)&ho[row * ESTRIDE + c * 8];
        if (use_res) {
            uint4 rv = sh[row * 16 + (c ^ (row & 7))];   // same bytes as res[R*16+c]
            v.x = hadd2u(v.x, rv.x); v.y = hadd2u(v.y, rv.y);
            v.z = hadd2u(v.z, rv.z); v.w = hadd2u(v.w, rv.w);
        }
        if (outb) {
            if (valid) outb[(size_t)R * 16 + c] = v;
        } else {
            // readout: sigmoid(h3 . Wo + bo); 16 consecutive lanes hold one row
            const float* wo = Wo + c * 8;
            f16x2 a0 = __builtin_bit_cast(f16x2, v.x);
            f16x2 a1 = __builtin_bit_cast(f16x2, v.y);
            f16x2 a2 = __builtin_bit_cast(f16x2, v.z);
            f16x2 a3 = __builtin_bit_cast(f16x2, v.w);
            float s = (float)a0.x * wo[0] + (float)a0.y * wo[1]
                    + (float)a1.x * wo[2] + (float)a1.y * wo[3]
                    + (float)a2.x * wo[4] + (float)a2.y * wo[5]
                    + (float)a3.x * wo[6] + (float)a3.y * wo[7];
#pragma unroll
            for (int o = 8; o; o >>= 1) s += __shfl_down(s, o, 16);
            if (valid && (t & 15) == 0)
                out[R] = 1.f / (1.f + expf(-(s + bo[0])));
        }
    }
}

// ---------------- launch ----------------

extern "C" void kernel_launch(void* const* d_in, const int* in_sizes, int n_in,
                              void* d_out, int out_size, void* d_ws, size_t ws_size,
                              hipStream_t stream) {
    const float* x   = (const float*)d_in[0];
    const int*   ei  = (const int*)d_in[1];
    const float* W1l = (const float*)d_in[2];
    const float* b1  = (const float*)d_in[3];
    const float* W1r = (const float*)d_in[4];
    const float* W2l = (const float*)d_in[5];
    const float* b2  = (const float*)d_in[6];
    const float* W2r = (const float*)d_in[7];
    const float* W3l = (const float*)d_in[8];
    const float* b3  = (const float*)d_in[9];
    const float* W3r = (const float*)d_in[10];
    const float* Wo  = (const float*)d_in[11];
    const float* bo  = (const float*)d_in[12];
    float* out = (float*)d_out;

    const int N_ = in_sizes[0] / HDIM;
    const int E_ = in_sizes[1] / 2;
    const int Np = (N_ + 127) & ~127;
    const int nbk = (N_ + BW - 1) / BW;   // 782 for N=100k

    size_t o = 0;
    auto carve = [&](size_t bytes) { size_t r = o; o = (o + bytes + 255) & ~255ULL; return r; };
    char* ws = (char*)d_ws;
    int* off        = (int*)(ws + carve((size_t)(N_ + 1) * 4));
    int* bucketCnt  = (int*)(ws + carve((size_t)NBKMAX * 4));
    int* srcs       = (int*)(ws + carve((size_t)E_ * 4));
    uint32* tmp     = (uint32*)(ws + carve((size_t)nbk * BCAP * 4));
    uint4* PW       = (uint4*)(ws + carve((size_t)3 * 4096 * 16));
    uint32* XB      = (uint32*)(ws + carve((size_t)Np * 64 * 4));  // x / h2
    uint32* H1B     = (uint32*)(ws + carve((size_t)Np * 64 * 4));  // h1
    (void)ws_size; (void)n_in; (void)out_size;

    // dispatch 1: zero bucket counts (4 KB)
    (void)hipMemsetAsync(bucketCnt, 0, (size_t)NBKMAX * 4, stream);

    // dispatch 2: prep = bucket-bin (first) | weights-pack | x-cast
    const int nbB = (E_ + CHUNK - 1) / CHUNK;        // 782 bin blocks
    const int nbW = (3 * 4096 + 255) / 256;          // 48 weight blocks
    const int nbX = (N_ * 64 + 255) / 256;           // 25000 x-cast blocks
    prep<<<nbB + nbW + nbX, 256, 0, stream>>>(
        x, ei, W1l, W1r, W2l, W2r, W3l, W3r,
        (f16x8*)PW, XB, bucketCnt, tmp, E_, N_, nbk, nbB, nbW);

    // dispatch 3: CSR finalize (inline base-scan + LDS sort, coalesced IO)
    bucket_csr<<<nbk, 256, 0, stream>>>(tmp, bucketCnt, off, srcs, N_, E_, nbk);

    const int nbF = (N_ + 31) / 32;     // fused blocks: 32 nodes each

    const uint4* PW1 = PW;
    const uint4* PW2 = PW + 4096;
    const uint4* PW3 = PW + 8192;

    // dispatches 4-6: fused layers
    // layer 1: h1 = elu(W1l m + b1 + W1r x)
    fused_layer<<<nbF, 256, 0, stream>>>(XB, off, srcs, (uint4*)H1B, PW1, b1,
                                         0, nullptr, nullptr, nullptr, N_);
    // layer 2: h2 = elu(...) + h1  -> XB
    fused_layer<<<nbF, 256, 0, stream>>>(H1B, off, srcs, (uint4*)XB, PW2, b2,
                                         1, nullptr, nullptr, nullptr, N_);
    // layer 3: h3 = elu(...) + h2, out = sigmoid(h3.Wo + bo) fused (no h3 store)
    fused_layer<<<nbF, 256, 0, stream>>>(XB, off, srcs, nullptr, PW3, b3,
                                         1, Wo, bo, out, N_);
}

// Round 11
// 343.075 us; speedup vs baseline: 1.0659x; 1.0659x over previous
//
#include <hip/hip_runtime.h>
#include <hip/hip_fp16.h>
#include <math.h>

#define HDIM 128

#define BSHIFT 7
#define BW 128                  // nodes per bucket (dst >> 7)
#define BCAP 4096               // slots per bucket (mean fill 2048, +45 sigma)
#define NBKMAX 1024
#define CHUNK 4096              // edges per binning block (R9 optimum; 2048 regressed)

typedef __attribute__((ext_vector_type(8))) _Float16 f16x8;
typedef __attribute__((ext_vector_type(2))) _Float16 f16x2;
typedef __attribute__((ext_vector_type(16))) float f32x16;
typedef unsigned int uint32;
typedef unsigned short u16;

// packed fp16 max -> v_pk_max_f16
__device__ __forceinline__ uint32 hmax2u(uint32 a, uint32 b) {
    f16x2 ha = __builtin_bit_cast(f16x2, a);
    f16x2 hb = __builtin_bit_cast(f16x2, b);
    f16x2 r = __builtin_elementwise_max(ha, hb);
    return __builtin_bit_cast(uint32, r);
}
// packed fp16 add -> v_pk_add_f16
__device__ __forceinline__ uint32 hadd2u(uint32 a, uint32 b) {
    f16x2 ha = __builtin_bit_cast(f16x2, a);
    f16x2 hb = __builtin_bit_cast(f16x2, b);
    f16x2 r = ha + hb;
    return __builtin_bit_cast(uint32, r);
}

// ---------------- prep: bucket-bin (FIRST) | weights-pack | x-cast ------------
// Bin role first: 391 heavy blocks start at t=0 on all CUs; tiny cast blocks
// backfill as they retire. Bin body = LDS-privatized two-pass (run-coalesced
// tmp writes — rounds 7/8 proved per-edge global-atomic scatter write-amps 2x).
// Cast role: float4 -> 2x half2 per thread (R11: halves cast block count).

__global__ __launch_bounds__(256) void prep(
    const float* __restrict__ x, const int* __restrict__ ei,
    const float* __restrict__ W1l, const float* __restrict__ W1r,
    const float* __restrict__ W2l, const float* __restrict__ W2r,
    const float* __restrict__ W3l, const float* __restrict__ W3r,
    f16x8* __restrict__ PW, uint32* __restrict__ xb,
    int* __restrict__ bucketCnt, uint32* __restrict__ tmp,
    int E_, int N_, int nbk, int nbB, int nbW)
{
    __shared__ int cnt[NBKMAX];
    __shared__ int gbase[NBKMAX];
    const int bid = blockIdx.x, t = threadIdx.x;

    if (bid < nbB) {
        // ---- bucket binning
        const int start = bid * CHUNK;
        const int end = min(start + CHUNK, E_);
        for (int i = t; i < nbk; i += 256) cnt[i] = 0;
        __syncthreads();
        for (int e = start + t; e < end; e += 256)
            atomicAdd(&cnt[ei[E_ + e] >> BSHIFT], 1);
        __syncthreads();
        for (int i = t; i < nbk; i += 256) {
            int c = cnt[i];
            gbase[i] = c ? atomicAdd(&bucketCnt[i], c) : 0;
        }
        __syncthreads();
        for (int i = t; i < nbk; i += 256) cnt[i] = 0;
        __syncthreads();
        for (int e = start + t; e < end; e += 256) {
            int d = ei[E_ + e];
            int s = ei[e];
            int b = d >> BSHIFT;
            int r = atomicAdd(&cnt[b], 1);
            tmp[(size_t)b * BCAP + gbase[b] + r] =
                ((uint32)(d & (BW - 1)) << 17) | (uint32)s;
        }
    } else if (bid < nbB + nbW) {
        // ---- weights: 3*4096 frags
        // PW[layer][(g*16+ks)*64+lane] = 16B frag; elements =
        // W[col=g*32+(lane&31)][(ks&7)*16 + (lane>>5)*8 + j], ks<8 -> Wl else Wr
        int tid = (bid - nbB) * 256 + t;
        if (tid >= 3 * 4096) return;
        int layer = tid >> 12, rem = tid & 4095;
        int g = rem >> 10, ks = (rem >> 6) & 15, lane = rem & 63;
        int col = g * 32 + (lane & 31), kq = lane >> 5;
        const float* src;
        if (layer == 0)      src = (ks < 8) ? W1l : W1r;
        else if (layer == 1) src = (ks < 8) ? W2l : W2r;
        else                 src = (ks < 8) ? W3l : W3r;
        int kk = (ks & 7) * 16 + kq * 8;
        f16x8 v;
#pragma unroll
        for (int j = 0; j < 8; ++j) v[j] = (_Float16)src[col * HDIM + kk + j];
        PW[tid] = v;
    } else {
        // ---- cast x -> packed half2 (float4 per thread)
        int i = (bid - nbB - nbW) * 256 + t;        // i indexes float4 / uint2
        if (i >= N_ * 32) return;
        float4 v = ((const float4*)x)[i];
        f16x2 h0 = { (_Float16)v.x, (_Float16)v.y };
        f16x2 h1 = { (_Float16)v.z, (_Float16)v.w };
        uint2 o;
        o.x = __builtin_bit_cast(uint32, h0);
        o.y = __builtin_bit_cast(uint32, h1);
        ((uint2*)xb)[i] = o;
    }
}

// ---------------- bucket_scan: 1-block prefix over 782 bucket counts ----------

__global__ __launch_bounds__(1024) void bucket_scan(
    const int* __restrict__ bucketCnt, int* __restrict__ bucketBase,
    int nbk, int* __restrict__ off, int N_, int E_) {
    __shared__ int sd[1024];
    int t = threadIdx.x;
    int v = (t < nbk) ? bucketCnt[t] : 0;
    sd[t] = v;
    __syncthreads();
    for (int ofs = 1; ofs < 1024; ofs <<= 1) {
        int add = (t >= ofs) ? sd[t - ofs] : 0;
        __syncthreads();
        sd[t] += add;
        __syncthreads();
    }
    if (t < nbk) bucketBase[t] = sd[t] - v;
    if (t == 0) off[N_] = E_;
}

// ---------------- bucket_csr: LDS-staged sort, fully coalesced global IO ------
// Rounds 7/8 lesson: scattered 4B GLOBAL writes cost a 64B write-allocate line
// each. Fix: stage the bucket in LDS, scatter in LDS, write srcs LINEARLY.

__global__ __launch_bounds__(256) void bucket_csr(
    const uint32* __restrict__ tmp, const int* __restrict__ bucketCnt,
    const int* __restrict__ bucketBase,
    int* __restrict__ off, int* __restrict__ srcs, int N_)
{
    __shared__ uint32 stmp[BCAP];    // 16 KB staged bucket entries
    __shared__ int sout[BCAP];       // 16 KB sorted srcs
    __shared__ int lc[BW];
    __shared__ int lo[BW];
    __shared__ int sd[256];
    const int b = blockIdx.x, t = threadIdx.x;
    const int cnt = bucketCnt[b], base = bucketBase[b];
    const uint32* tp = tmp + (size_t)b * BCAP;

    // stage bucket (coalesced reads)
    for (int i = t; i < cnt; i += 256) stmp[i] = tp[i];
    if (t < BW) lc[t] = 0;
    __syncthreads();

    // per-node histogram (LDS atomics on LDS data)
    for (int i = t; i < cnt; i += 256) atomicAdd(&lc[stmp[i] >> 17], 1);
    __syncthreads();

    // 128-bin exclusive scan
    int v = (t < BW) ? lc[t] : 0;
    sd[t] = v;
    __syncthreads();
    for (int ofs = 1; ofs < 256; ofs <<= 1) {
        int add = (t >= ofs) ? sd[t - ofs] : 0;
        __syncthreads();
        sd[t] += add;
        __syncthreads();
    }
    if (t < BW) lo[t] = sd[t] - v;
    __syncthreads();

    // node offsets (coalesced)
    for (int i = t; i < BW; i += 256) {
        int node = b * BW + i;
        if (node < N_) off[node] = base + lo[i];
    }
    if (t < BW) lc[t] = lo[t];
    __syncthreads();

    // scatter WITHIN LDS (cheap), then linear coalesced global store
    for (int i = t; i < cnt; i += 256) {
        uint32 p = stmp[i];
        int pos = atomicAdd(&lc[p >> 17], 1);
        sout[pos] = (int)(p & 0x1FFFF);
    }
    __syncthreads();
    for (int i = t; i < cnt; i += 256) srcs[base + i] = sout[i];
}

// ---------------- fused layer (verbatim round-5/9 structure — DO NOT TOUCH) ---
// gather-max (LDS-staged edge indices + software-pipelined feature loads)
//   -> GEMM -> ELU(+res from staged sh tile) [-> readout]
// At its pattern ceiling: 186 MB L2-fill at the ~3.2-3.5 TB/s random-256B rate
// (reproduced across 6 structures, R0/R1/R2/R5/R9/R10) ~= the 68.5 us measured.
//
// LDS: sm/ho overlay 8704 + sh 8192 + soff 132 + sedge 3328 = 20356 B.
// launch_bounds(256,6): VGPR cap ~84 so the vb[2][4] pipeline (needs ~60)
// actually lives in registers (cap 64 sank it: VGPR=32 + scratch spills).

#define ESTRIDE 136     // halves per epilogue LDS row (272 B)
#define EDGE_CAP 832    // staged edges per block (mean 512, std 22.6 -> +14 sigma)

#define RED16(m0,m1,m2,m3,V) do { \
    m0 = hmax2u(m0, (V)[0].x); m1 = hmax2u(m1, (V)[0].y); \
    m2 = hmax2u(m2, (V)[0].z); m3 = hmax2u(m3, (V)[0].w); \
    m0 = hmax2u(m0, (V)[1].x); m1 = hmax2u(m1, (V)[1].y); \
    m2 = hmax2u(m2, (V)[1].z); m3 = hmax2u(m3, (V)[1].w); \
    m0 = hmax2u(m0, (V)[2].x); m1 = hmax2u(m1, (V)[2].y); \
    m2 = hmax2u(m2, (V)[2].z); m3 = hmax2u(m3, (V)[2].w); \
    m0 = hmax2u(m0, (V)[3].x); m1 = hmax2u(m1, (V)[3].y); \
    m2 = hmax2u(m2, (V)[3].z); m3 = hmax2u(m3, (V)[3].w); \
} while (0)

// issue one 16-edge batch (4 uint4/lane), edge indices clamped to [*, e1-1]
// (duplicates are idempotent under max); L=true reads indices from LDS.
template<bool L>
__device__ __forceinline__ void issue_batch(
    const uint4* __restrict__ hp, const int* __restrict__ srcs,
    const int* sedge, int estart, int eb, int e1, int es, int ch, uint4* v)
{
    int last = e1 - 1;
#pragma unroll
    for (int k = 0; k < 4; ++k) {
        int idx = min(eb + es + 4 * k, last);
        int s = L ? sedge[idx - estart] : srcs[idx];
        v[k] = hp[(size_t)s * 16 + ch];
    }
}

template<bool L>
__device__ __forceinline__ void gather8(
    const uint4* __restrict__ hp, const int* __restrict__ srcs,
    const int* sedge, int estart, int offv, int es, int ch, int w,
    uint4* sm)
{
    const uint32 NINF = 0xFC00FC00u;   // half2(-inf,-inf)
    uint4 vb[2][4];

    int e0 = __shfl(offv, 0), e1 = __shfl(offv, 1);
    bool has = e1 > e0;
    if (has) issue_batch<L>(hp, srcs, sedge, estart, e0, e1, es, ch, vb[0]);

#pragma unroll
    for (int i = 0; i < 8; ++i) {
        // prefetch next node's first batch while current reduces
        int e0n = 0, e1n = 0; bool hasn = false;
        if (i + 1 < 8) {
            e0n = __shfl(offv, i + 1); e1n = __shfl(offv, i + 2);
            hasn = e1n > e0n;
            if (hasn) issue_batch<L>(hp, srcs, sedge, estart, e0n, e1n, es, ch, vb[(i + 1) & 1]);
        }
        uint32 m0 = NINF, m1 = NINF, m2 = NINF, m3 = NINF;
        if (has) {
            RED16(m0, m1, m2, m3, vb[i & 1]);
            for (int eb = e0 + 16; eb < e1; eb += 16) {   // extra batches (deg>16)
                issue_batch<L>(hp, srcs, sedge, estart, eb, e1, es, ch, vb[i & 1]);
                RED16(m0, m1, m2, m3, vb[i & 1]);
            }
        }
        m0 = hmax2u(m0, __shfl_xor(m0, 16)); m0 = hmax2u(m0, __shfl_xor(m0, 32));
        m1 = hmax2u(m1, __shfl_xor(m1, 16)); m1 = hmax2u(m1, __shfl_xor(m1, 32));
        m2 = hmax2u(m2, __shfl_xor(m2, 16)); m2 = hmax2u(m2, __shfl_xor(m2, 32));
        m3 = hmax2u(m3, __shfl_xor(m3, 16)); m3 = hmax2u(m3, __shfl_xor(m3, 32));
        if (es == 0) {
            int row = w * 8 + i;
            uint4 rr = make_uint4(0u, 0u, 0u, 0u);   // empty/padded -> 0 (PyG)
            if (has) { rr.x = m0; rr.y = m1; rr.z = m2; rr.w = m3; }
            sm[row * 16 + (ch ^ (row & 7))] = rr;
        }
        e0 = e0n; e1 = e1n; has = hasn;
    }
}

__global__ __launch_bounds__(256, 6) void fused_layer(
    const uint32* __restrict__ hb,      // [Np,64] input features, packed half2
    const int* __restrict__ off, const int* __restrict__ srcs,
    uint4* __restrict__ outb,           // layer output (null => readout mode)
    const uint4* __restrict__ PW,       // [4096] packed weight frags, this layer
    const float* __restrict__ bias,
    int use_res,
    const float* __restrict__ Wo, const float* __restrict__ bo,
    float* __restrict__ out, int n_nodes)
{
    __shared__ alignas(16) char smemA[32 * ESTRIDE * 2];  // 8704 B: sm / ho overlay
    __shared__ uint4 sh[512];                             // 8192 B: h-tile
    __shared__ int soff[33];                              // 132 B
    __shared__ int sedge[EDGE_CAP];                       // 3328 B
    uint4*     sm = (uint4*)smemA;
    _Float16*  ho = (_Float16*)smemA;

    const int t = threadIdx.x, lane = t & 63, w = t >> 6;
    const int base = blockIdx.x * 32;
    const int l31 = lane & 31, kq = lane >> 5;
    const uint4* hp = (const uint4*)hb;

    // stage off[] window
    if (t < 33) soff[t] = off[min(base + t, n_nodes)];

    // stage h-tile, coalesced, swizzled (loads overlap edge staging)
#pragma unroll
    for (int r = 0; r < 2; ++r) {
        int g = r * 256 + t;            // 0..511
        int row = g >> 4, c = g & 15;
        sh[row * 16 + (c ^ (row & 7))] = hp[(size_t)(base + row) * 16 + c];
    }

    // stage the block's contiguous CSR edge range into LDS (coalesced)
    const int estart = off[base];
    const int eend = off[min(base + 32, n_nodes)];
    const int ecnt = eend - estart;
    const bool useLds = (ecnt <= EDGE_CAP);   // block-uniform
    const int scount = useLds ? ecnt : 0;
    for (int i = t; i < scount; i += 256) sedge[i] = srcs[estart + i];
    __syncthreads();

    // gather-max: each wave aggregates 8 nodes, result into swizzled sm
    const int es = lane >> 4, ch = lane & 15;
    const int offv = soff[w * 8 + min(lane, 8)];
    if (useLds) gather8<true >(hp, srcs, sedge, estart, offv, es, ch, w, sm);
    else        gather8<false>(hp, srcs, sedge, estart, offv, es, ch, w, sm);
    __syncthreads();

    f32x16 acc = {};
#pragma unroll
    for (int k = 0; k < 8; ++k) {   // m half, K=0..127
        f16x8 a = __builtin_bit_cast(f16x8, sm[l31 * 16 + ((2 * k + kq) ^ (l31 & 7))]);
        f16x8 b = __builtin_bit_cast(f16x8, PW[(w * 16 + k) * 64 + lane]);
        acc = __builtin_amdgcn_mfma_f32_32x32x16_f16(a, b, acc, 0, 0, 0);
    }
#pragma unroll
    for (int k = 0; k < 8; ++k) {   // h half, K=128..255
        f16x8 a = __builtin_bit_cast(f16x8, sh[l31 * 16 + ((2 * k + kq) ^ (l31 & 7))]);
        f16x8 b = __builtin_bit_cast(f16x8, PW[(w * 16 + 8 + k) * 64 + lane]);
        acc = __builtin_amdgcn_mfma_f32_32x32x16_f16(a, b, acc, 0, 0, 0);
    }

    __syncthreads();   // all waves done reading sm before ho overlay is written

    // epilogue phase 1: bias + ELU in fp32, fp16 into LDS transpose tile
    // C/D layout (32x32): col = lane&31, row = (reg&3)+8*(reg>>2)+4*(lane>>5)
    const int C = w * 32 + l31;
    const float bv = bias[C];
#pragma unroll
    for (int r = 0; r < 16; ++r) {
        int row = (r & 3) + 8 * (r >> 2) + 4 * kq;
        float v = acc[r] + bv;
        v = (v > 0.f) ? v : (__expf(v) - 1.f);
        ho[row * ESTRIDE + C] = (_Float16)v;
    }
    __syncthreads();

    // epilogue phase 2: residual from staged sh tile; store row-major uint4,
    // or (layer 3) fused readout without materializing h3.
#pragma unroll
    for (int r = 0; r < 2; ++r) {
        int g = r * 256 + t;            // 0..511
        int row = g >> 4, c = g & 15;
        int R = base + row;
        bool valid = (R < n_nodes);
        uint4 v = *(const uint4*)&ho[row * ESTRIDE + c * 8];
        if (use_res) {
            uint4 rv = sh[row * 16 + (c ^ (row & 7))];   // same bytes as res[R*16+c]
            v.x = hadd2u(v.x, rv.x); v.y = hadd2u(v.y, rv.y);
            v.z = hadd2u(v.z, rv.z); v.w = hadd2u(v.w, rv.w);
        }
        if (outb) {
            if (valid) outb[(size_t)R * 16 + c] = v;
        } else {
            // readout: sigmoid(h3 . Wo + bo); 16 consecutive lanes hold one row
            const float* wo = Wo + c * 8;
            f16x2 a0 = __builtin_bit_cast(f16x2, v.x);
            f16x2 a1 = __builtin_bit_cast(f16x2, v.y);
            f16x2 a2 = __builtin_bit_cast(f16x2, v.z);
            f16x2 a3 = __builtin_bit_cast(f16x2, v.w);
            float s = (float)a0.x * wo[0] + (float)a0.y * wo[1]
                    + (float)a1.x * wo[2] + (float)a1.y * wo[3]
                    + (float)a2.x * wo[4] + (float)a2.y * wo[5]
                    + (float)a3.x * wo[6] + (float)a3.y * wo[7];
#pragma unroll
            for (int o = 8; o; o >>= 1) s += __shfl_down(s, o, 16);
            if (valid && (t & 15) == 0)
                out[R] = 1.f / (1.f + expf(-(s + bo[0])));
        }
    }
}

// ---------------- launch ----------------

extern "C" void kernel_launch(void* const* d_in, const int* in_sizes, int n_in,
                              void* d_out, int out_size, void* d_ws, size_t ws_size,
                              hipStream_t stream) {
    const float* x   = (const float*)d_in[0];
    const int*   ei  = (const int*)d_in[1];
    const float* W1l = (const float*)d_in[2];
    const float* b1  = (const float*)d_in[3];
    const float* W1r = (const float*)d_in[4];
    const float* W2l = (const float*)d_in[5];
    const float* b2  = (const float*)d_in[6];
    const float* W2r = (const float*)d_in[7];
    const float* W3l = (const float*)d_in[8];
    const float* b3  = (const float*)d_in[9];
    const float* W3r = (const float*)d_in[10];
    const float* Wo  = (const float*)d_in[11];
    const float* bo  = (const float*)d_in[12];
    float* out = (float*)d_out;

    const int N_ = in_sizes[0] / HDIM;
    const int E_ = in_sizes[1] / 2;
    const int Np = (N_ + 127) & ~127;
    const int nbk = (N_ + BW - 1) / BW;   // 782 for N=100k

    size_t o = 0;
    auto carve = [&](size_t bytes) { size_t r = o; o = (o + bytes + 255) & ~255ULL; return r; };
    char* ws = (char*)d_ws;
    int* off        = (int*)(ws + carve((size_t)(N_ + 1) * 4));
    int* bucketCnt  = (int*)(ws + carve((size_t)NBKMAX * 4));
    int* bucketBase = (int*)(ws + carve((size_t)NBKMAX * 4));
    int* srcs       = (int*)(ws + carve((size_t)E_ * 4));
    uint32* tmp     = (uint32*)(ws + carve((size_t)nbk * BCAP * 4));
    uint4* PW       = (uint4*)(ws + carve((size_t)3 * 4096 * 16));
    uint32* XB      = (uint32*)(ws + carve((size_t)Np * 64 * 4));  // x / h2
    uint32* H1B     = (uint32*)(ws + carve((size_t)Np * 64 * 4));  // h1
    (void)ws_size; (void)n_in; (void)out_size;

    // dispatch 1: zero bucket counts (4 KB)
    (void)hipMemsetAsync(bucketCnt, 0, (size_t)NBKMAX * 4, stream);

    // dispatch 2: prep = bucket-bin (first) | weights-pack | x-cast
    const int nbB = (E_ + CHUNK - 1) / CHUNK;        // 391 bin blocks
    const int nbW = (3 * 4096 + 255) / 256;          // 48 weight blocks
    const int nbX = (N_ * 32 + 255) / 256;           // 12500 x-cast blocks (float4/thread)
    prep<<<nbB + nbW + nbX, 256, 0, stream>>>(
        x, ei, W1l, W1r, W2l, W2r, W3l, W3r,
        (f16x8*)PW, XB, bucketCnt, tmp, E_, N_, nbk, nbB, nbW);

    // dispatch 3: bucket-base scan (1 block over 782 counts)
    bucket_scan<<<1, 1024, 0, stream>>>(bucketCnt, bucketBase, nbk, off, N_, E_);

    // dispatch 4: CSR finalize — LDS-staged sort, coalesced global IO
    bucket_csr<<<nbk, 256, 0, stream>>>(tmp, bucketCnt, bucketBase, off, srcs, N_);

    const int nbF = (N_ + 31) / 32;     // fused blocks: 32 nodes each

    const uint4* PW1 = PW;
    const uint4* PW2 = PW + 4096;
    const uint4* PW3 = PW + 8192;

    // dispatches 5-7: fused layers
    // layer 1: h1 = elu(W1l m + b1 + W1r x)
    fused_layer<<<nbF, 256, 0, stream>>>(XB, off, srcs, (uint4*)H1B, PW1, b1,
                                         0, nullptr, nullptr, nullptr, N_);
    // layer 2: h2 = elu(...) + h1  -> XB
    fused_layer<<<nbF, 256, 0, stream>>>(H1B, off, srcs, (uint4*)XB, PW2, b2,
                                         1, nullptr, nullptr, nullptr, N_);
    // layer 3: h3 = elu(...) + h2, out = sigmoid(h3.Wo + bo) fused (no h3 store)
    fused_layer<<<nbF, 256, 0, stream>>>(XB, off, srcs, nullptr, PW3, b3,
                                         1, Wo, bo, out, N_);
}